// Round 3
// baseline (468.446 us; speedup 1.0000x reference)
//
#include <hip/hip_runtime.h>
#include <math.h>

// Problem constants
#define NQ     65536
#define DIM    256
#define NBATCH 512
#define KNN    200
#define NCLS   1000
#define TSEL   0.14f     // candidate threshold (top-200 boundary ~0.17; fallback covers misses)

typedef unsigned short u16;
typedef unsigned long long u64;
typedef __attribute__((ext_vector_type(8))) short short8;
typedef __attribute__((ext_vector_type(4))) float f32x4;

// out layout: [0] accuracy | [1..1+NQ*DIM) features | [..+NQ) labels | [last] ptr

__device__ __forceinline__ u16 f2bf(float x) {
  unsigned u = __float_as_uint(x);
  return (u16)((u + 0x7FFFu + ((u >> 16) & 1u)) >> 16);
}
__device__ __forceinline__ float bf2f(u16 h) {
  return __uint_as_float(((unsigned)h) << 16);
}
__device__ __forceinline__ void load_lds16(const void* g, void* l) {
  __builtin_amdgcn_global_load_lds(
      (const __attribute__((address_space(1))) unsigned int*)g,
      (__attribute__((address_space(3))) unsigned int*)l, 16, 0, 0);
}

// ---------------------------------------------------------------------------
// 0. prep: split A/B into bf16 hi/lo; zero accuracy + cnt/flag scratch
// ---------------------------------------------------------------------------
__global__ __launch_bounds__(256) void prep_kernel(
    const float* __restrict__ feat, const float* __restrict__ qf,
    u16* __restrict__ Bhi, u16* __restrict__ Blo,
    u16* __restrict__ Ahi, u16* __restrict__ Alo,
    int* __restrict__ misc, float* __restrict__ out)
{
  int idx = blockIdx.x * 256 + threadIdx.x;
  const int NB4 = NQ * DIM / 4;
  const int NA4 = NBATCH * DIM / 4;
  if (idx < NB4) {
    float4 v = ((const float4*)qf)[idx];
    ushort4 h, l;
    h.x = f2bf(v.x); l.x = f2bf(v.x - bf2f(h.x));
    h.y = f2bf(v.y); l.y = f2bf(v.y - bf2f(h.y));
    h.z = f2bf(v.z); l.z = f2bf(v.z - bf2f(h.z));
    h.w = f2bf(v.w); l.w = f2bf(v.w - bf2f(h.w));
    ((ushort4*)Bhi)[idx] = h;
    ((ushort4*)Blo)[idx] = l;
  } else if (idx < NB4 + NA4) {
    int j = idx - NB4;
    float4 v = ((const float4*)feat)[j];
    ushort4 h, l;
    h.x = f2bf(v.x); l.x = f2bf(v.x - bf2f(h.x));
    h.y = f2bf(v.y); l.y = f2bf(v.y - bf2f(h.y));
    h.z = f2bf(v.z); l.z = f2bf(v.z - bf2f(h.z));
    h.w = f2bf(v.w); l.w = f2bf(v.w - bf2f(h.w));
    ((ushort4*)Ahi)[j] = h;
    ((ushort4*)Alo)[j] = l;
  }
  if (idx < 2 * NBATCH) misc[idx] = 0;      // cnt[512] + flag[512]
  if (idx == 0) out[0] = 0.0f;
}

// ---------------------------------------------------------------------------
// 1. split-bf16 MFMA GEMM with threshold-append epilogue (no C matrix).
//    128x128 tile, BK=32, 4 waves; XCD-aware swizzle: same-bn blocks spaced
//    by 8 dispatch ids -> same XCD -> B tile fetched once per L2.
// ---------------------------------------------------------------------------
#define GM 128
#define GK 32

__global__ __launch_bounds__(256) void gemm_mfma(
    const u16* __restrict__ Ahi, const u16* __restrict__ Alo,
    const u16* __restrict__ Bhi, const u16* __restrict__ Blo,
    uint2* __restrict__ cand, int* __restrict__ cnt, int CAP)
{
  __shared__ u16 sA[2][GM][GK];
  __shared__ u16 sB[2][GM][GK];

  const int tid  = threadIdx.x;
  const int wave = tid >> 6, lane = tid & 63;
  // swizzle: d = ((bn>>3)*4 + bm)*8 + (bn&7)  => bm strides of 8 share an XCD
  const int d  = blockIdx.x;
  const int bm = (d >> 3) & 3;
  const int bn = (d & 7) | ((d >> 5) << 3);

  const u16* srcBase;
  u16* ldsBase;
  if (wave == 0)      { srcBase = Ahi + (size_t)bm * GM * DIM; ldsBase = &sA[0][0][0]; }
  else if (wave == 1) { srcBase = Alo + (size_t)bm * GM * DIM; ldsBase = &sA[1][0][0]; }
  else if (wave == 2) { srcBase = Bhi + (size_t)bn * GM * DIM; ldsBase = &sB[0][0][0]; }
  else                { srcBase = Blo + (size_t)bn * GM * DIM; ldsBase = &sB[1][0][0]; }
  const u16* src = srcBase + (lane >> 2) * DIM + (lane & 3) * 8;

  const int wm = (wave & 1) * 64, wn = (wave >> 1) * 64;
  const int fr = lane & 15;
  const int fq = lane >> 4;

  f32x4 acc[4][4] = {};

  for (int kk = 0; kk < DIM; kk += GK) {
    const u16* s = src + kk;
#pragma unroll
    for (int g = 0; g < 8; ++g)
      load_lds16(s + g * 16 * DIM, ldsBase + g * 512);
    __syncthreads();

    short8 ah[4], al[4], bh[4], bl[4];
#pragma unroll
    for (int i = 0; i < 4; ++i) {
      ah[i] = *(const short8*)&sA[0][wm + i * 16 + fr][fq * 8];
      al[i] = *(const short8*)&sA[1][wm + i * 16 + fr][fq * 8];
      bh[i] = *(const short8*)&sB[0][wn + i * 16 + fr][fq * 8];
      bl[i] = *(const short8*)&sB[1][wn + i * 16 + fr][fq * 8];
    }
#pragma unroll
    for (int i = 0; i < 4; ++i)
#pragma unroll
      for (int j = 0; j < 4; ++j) {
        acc[i][j] = __builtin_amdgcn_mfma_f32_16x16x32_bf16(ah[i], bh[j], acc[i][j], 0, 0, 0);
        acc[i][j] = __builtin_amdgcn_mfma_f32_16x16x32_bf16(ah[i], bl[j], acc[i][j], 0, 0, 0);
        acc[i][j] = __builtin_amdgcn_mfma_f32_16x16x32_bf16(al[i], bh[j], acc[i][j], 0, 0, 0);
        acc[i][j] = __builtin_amdgcn_mfma_f32_16x16x32_bf16(al[i], bl[j], acc[i][j], 0, 0, 0);
      }
    __syncthreads();
  }

  // epilogue: D row = fq*4+r, col = fr (verified). Append survivors.
  const int crow = bm * GM + wm + fq * 4;
  const int ccol = bn * GM + wn + fr;
#pragma unroll
  for (int i = 0; i < 4; ++i)
#pragma unroll
    for (int j = 0; j < 4; ++j)
#pragma unroll
      for (int r = 0; r < 4; ++r) {
        float v = acc[i][j][r];
        if (v > TSEL) {
          int row = crow + i * 16 + r;
          int col = ccol + j * 16;
          int p = atomicAdd(&cnt[row], 1);
          if (p < CAP)
            cand[(size_t)row * CAP + p] = make_uint2(__float_as_uint(v), (unsigned)col);
        }
      }
}

// ---------------------------------------------------------------------------
// 2. select: per row, exact top-200 from ~800 candidates.
// ---------------------------------------------------------------------------
#define NBSEL 2048
#define SCAP  1024

__global__ __launch_bounds__(256) void select_kernel(
    const uint2* __restrict__ cand, const int* __restrict__ cnt,
    int* __restrict__ flag, const int* __restrict__ labels,
    const int* __restrict__ qlab, float* __restrict__ out,
    float inv_n, int CAP)
{
  __shared__ int  hist[NBSEL];
  __shared__ int  seg[256];
  __shared__ u64  ck[SCAP];
  __shared__ float votes[NCLS];
  __shared__ int  s_b, s_cnt;
  __shared__ u64  s_best;

  const int tid = threadIdx.x;
  const int row = blockIdx.x;
  const int n = cnt[row];
  if (n < KNN || n > CAP) { if (tid == 0) flag[row] = 1; return; }

  const uint2* crow = cand + (size_t)row * CAP;
  const float SSCALE = (float)NBSEL / (1.001f - TSEL);

  for (int i = tid; i < NBSEL; i += 256) hist[i] = 0;
  if (tid == 0) { s_b = 0; s_cnt = 0; s_best = 0ull; }
  __syncthreads();

  for (int i = tid; i < n; i += 256) {
    float v = __uint_as_float(crow[i].x);
    int b = (int)((v - TSEL) * SSCALE);
    b = b < 0 ? 0 : (b > NBSEL - 1 ? NBSEL - 1 : b);
    atomicAdd(&hist[b], 1);
  }
  __syncthreads();

  { int s = 0;
#pragma unroll
    for (int i = 0; i < 8; ++i) s += hist[tid * 8 + i];
    seg[tid] = s; }
  __syncthreads();
  for (int off = 1; off < 256; off <<= 1) {
    int t = (tid + off < 256) ? seg[tid + off] : 0;
    __syncthreads();
    seg[tid] += t;
    __syncthreads();
  }
  { int run = (tid < 255) ? seg[tid + 1] : 0;
    for (int i = tid * 8 + 7; i >= tid * 8; --i) {
      run += hist[i];
      if (run >= KNN) { atomicMax(&s_b, i); break; }
    } }
  __syncthreads();
  const int bstar = s_b;

  for (int i = tid; i < n; i += 256) {
    float v = __uint_as_float(crow[i].x);
    int b = (int)((v - TSEL) * SSCALE);
    b = b < 0 ? 0 : (b > NBSEL - 1 ? NBSEL - 1 : b);
    if (b >= bstar) {
      int p = atomicAdd(&s_cnt, 1);
      if (p < SCAP)
        ck[p] = ((u64)crow[i].x << 32) | (u64)(0xFFFFFFFFu - crow[i].y);
    }
  }
  __syncthreads();
  int m = s_cnt;
  if (m > SCAP) { if (tid == 0) flag[row] = 1; return; }

  int P = 256; while (P < m) P <<= 1;
  for (int i = tid; i < P; i += 256) if (i >= m) ck[i] = 0ull;
  __syncthreads();
  for (int k = 2; k <= P; k <<= 1) {
    for (int j = k >> 1; j > 0; j >>= 1) {
      for (int i = tid; i < P; i += 256) {
        int ixj = i ^ j;
        if (ixj > i) {
          u64 a = ck[i], b = ck[ixj];
          bool up = ((i & k) == 0);         // descending
          if (up ? (a < b) : (a > b)) { ck[i] = b; ck[ixj] = a; }
        }
      }
      __syncthreads();
    }
  }

  for (int c = tid; c < NCLS; c += 256) votes[c] = 0.0f;
  __syncthreads();
  for (int i = tid; i < KNN; i += 256) {
    u64 key = ck[i];
    float v = __uint_as_float((unsigned)(key >> 32));
    int col = (int)(0xFFFFFFFFu - (unsigned)(key & 0xFFFFFFFFull));
    atomicAdd(&votes[qlab[col]], expf(v * (1.0f / 0.07f)));
  }
  __syncthreads();

  u64 key = 0ull;
  for (int c = tid; c < NCLS; c += 256) {
    u64 k2 = ((u64)__float_as_uint(votes[c]) << 32) |
             (u64)(0xFFFFFFFFu - (unsigned)c);
    if (k2 > key) key = k2;
  }
  for (int off = 32; off > 0; off >>= 1) {
    u64 o = __shfl_down(key, off, 64);
    if (o > key) key = o;
  }
  if ((tid & 63) == 0) atomicMax(&s_best, key);
  __syncthreads();
  if (tid == 0) {
    int cls = (int)(0xFFFFFFFFu - (unsigned)(s_best & 0xFFFFFFFFull));
    if (cls == labels[row]) atomicAdd(out, inv_n);
  }
}

// ---------------------------------------------------------------------------
// 2b. fallback: exact f32 recompute + selection for flagged rows (rare/never).
// ---------------------------------------------------------------------------
#define FCAP 2048

__global__ __launch_bounds__(256) void fallback_kernel(
    const float* __restrict__ feat, const int* __restrict__ labels,
    const float* __restrict__ qf, const int* __restrict__ qlab,
    const int* __restrict__ flag, float* __restrict__ out, float inv_n)
{
  const int row = blockIdx.x;
  if (!flag[row]) return;

  __shared__ float frow[DIM];
  __shared__ int   hist[NBSEL];
  __shared__ int   seg[256];
  __shared__ float candV[FCAP];
  __shared__ int   candI[FCAP];
  __shared__ float votes[NCLS];
  __shared__ int   s_b, s_cnt;
  __shared__ u64   s_best;

  const int tid = threadIdx.x;
  frow[tid] = feat[(size_t)row * DIM + tid];
  for (int i = tid; i < NBSEL; i += 256) hist[i] = 0;
  if (tid == 0) { s_b = 0; s_cnt = 0; s_best = 0ull; }
  __syncthreads();

  // pass 1: histogram of exact f32 dots, bins over [-1,1]
  for (int q = tid; q < NQ; q += 256) {
    const float4* qr = (const float4*)(qf + (size_t)q * DIM);
    const float4* fr = (const float4*)frow;
    float s = 0.0f;
#pragma unroll
    for (int t = 0; t < DIM / 4; ++t) {
      float4 a = fr[t], b = qr[t];
      s = fmaf(a.x, b.x, s); s = fmaf(a.y, b.y, s);
      s = fmaf(a.z, b.z, s); s = fmaf(a.w, b.w, s);
    }
    int bin = (int)((s + 1.0f) * (NBSEL * 0.5f));
    bin = bin < 0 ? 0 : (bin > NBSEL - 1 ? NBSEL - 1 : bin);
    atomicAdd(&hist[bin], 1);
  }
  __syncthreads();

  { int s = 0;
#pragma unroll
    for (int i = 0; i < 8; ++i) s += hist[tid * 8 + i];
    seg[tid] = s; }
  __syncthreads();
  for (int off = 1; off < 256; off <<= 1) {
    int t = (tid + off < 256) ? seg[tid + off] : 0;
    __syncthreads();
    seg[tid] += t;
    __syncthreads();
  }
  { int run = (tid < 255) ? seg[tid + 1] : 0;
    for (int i = tid * 8 + 7; i >= tid * 8; --i) {
      run += hist[i];
      if (run >= KNN) { atomicMax(&s_b, i); break; }
    } }
  __syncthreads();
  const int bstar = s_b;

  // pass 2: recompute, collect
  for (int q = tid; q < NQ; q += 256) {
    const float4* qr = (const float4*)(qf + (size_t)q * DIM);
    const float4* fr = (const float4*)frow;
    float s = 0.0f;
#pragma unroll
    for (int t = 0; t < DIM / 4; ++t) {
      float4 a = fr[t], b = qr[t];
      s = fmaf(a.x, b.x, s); s = fmaf(a.y, b.y, s);
      s = fmaf(a.z, b.z, s); s = fmaf(a.w, b.w, s);
    }
    int bin = (int)((s + 1.0f) * (NBSEL * 0.5f));
    bin = bin < 0 ? 0 : (bin > NBSEL - 1 ? NBSEL - 1 : bin);
    if (bin >= bstar) {
      int p = atomicAdd(&s_cnt, 1);
      if (p < FCAP) { candV[p] = s; candI[p] = q; }
    }
  }
  __syncthreads();
  int m = s_cnt < FCAP ? s_cnt : FCAP;

  int P = 256; while (P < m) P <<= 1;
  for (int i = tid; i < P; i += 256)
    if (i >= m) { candV[i] = -INFINITY; candI[i] = 0x7fffffff; }
  __syncthreads();
  for (int k = 2; k <= P; k <<= 1) {
    for (int j = k >> 1; j > 0; j >>= 1) {
      for (int i = tid; i < P; i += 256) {
        int ixj = i ^ j;
        if (ixj > i) {
          float va = candV[i], vb = candV[ixj];
          int ia = candI[i], ib = candI[ixj];
          bool aFirst = (va > vb) || (va == vb && ia < ib);
          bool up = ((i & k) == 0);
          if (up ? !aFirst : aFirst) {
            candV[i] = vb; candV[ixj] = va;
            candI[i] = ib; candI[ixj] = ia;
          }
        }
      }
      __syncthreads();
    }
  }

  for (int c = tid; c < NCLS; c += 256) votes[c] = 0.0f;
  __syncthreads();
  for (int i = tid; i < KNN; i += 256)
    atomicAdd(&votes[qlab[candI[i]]], expf(candV[i] * (1.0f / 0.07f)));
  __syncthreads();

  u64 key = 0ull;
  for (int c = tid; c < NCLS; c += 256) {
    u64 k2 = ((u64)__float_as_uint(votes[c]) << 32) |
             (u64)(0xFFFFFFFFu - (unsigned)c);
    if (k2 > key) key = k2;
  }
  for (int off = 32; off > 0; off >>= 1) {
    u64 o = __shfl_down(key, off, 64);
    if (o > key) key = o;
  }
  if ((tid & 63) == 0) atomicMax(&s_best, key);
  __syncthreads();
  if (tid == 0) {
    int cls = (int)(0xFFFFFFFFu - (unsigned)(s_best & 0xFFFFFFFFull));
    if (cls == labels[row]) atomicAdd(out, inv_n);
  }
}

// ---------------------------------------------------------------------------
// 3. final copy / queue update (LAST: overwrites B staging in out region)
// ---------------------------------------------------------------------------
__global__ __launch_bounds__(256) void copy_kernel(
    const float* __restrict__ feat, const int* __restrict__ labels,
    const float* __restrict__ qf, const int* __restrict__ ql,
    const int* __restrict__ qptr, float* __restrict__ out)
{
  const long long NFEAT = (long long)NQ * DIM;
  long long idx = (long long)blockIdx.x * blockDim.x + threadIdx.x;
  int ptr = qptr[0];

  if (idx < NFEAT) {
    long long row = idx >> 8;
    int col = (int)(idx & (DIM - 1));
    int d = ((int)row - ptr) & (NQ - 1);
    float v = (d < NBATCH) ? feat[(long long)d * DIM + col] : qf[idx];
    out[1 + idx] = v;
  } else if (idx < NFEAT + NQ) {
    int i = (int)(idx - NFEAT);
    int d = (i - ptr) & (NQ - 1);
    int v = (d < NBATCH) ? labels[d] : ql[i];
    out[1 + NFEAT + i] = (float)v;
  }
  if (idx == 0)
    out[1 + NFEAT + NQ] = (float)((ptr + NBATCH) & (NQ - 1));
}

// ---------------------------------------------------------------------------
extern "C" void kernel_launch(void* const* d_in, const int* in_sizes, int n_in,
                              void* d_out, int out_size, void* d_ws, size_t ws_size,
                              hipStream_t stream)
{
  const float* features = (const float*)d_in[0];
  const int*   labels   = (const int*)d_in[1];
  const float* qfeat    = (const float*)d_in[2];
  const int*   qlab     = (const int*)d_in[3];
  const int*   qptr     = (const int*)d_in[4];
  float* out = (float*)d_out;

  int nbatch = in_sizes[0] / DIM;             // 512
  float inv_n = 1.0f / (float)nbatch;

  // B hi/lo staged in out's feature region (overwritten by copy_kernel last)
  u16* Bhi = (u16*)(out + 4);
  u16* Blo = Bhi + (size_t)NQ * DIM;

  // ws: [cand 512*CAP*8][cnt 512][flag 512][Ahi][Alo]; CAP sized to fit
  size_t fixed = (size_t)2 * NBATCH * 4 + (size_t)NBATCH * DIM * 2 * 2;
  int CAP = 8192;
  while ((size_t)NBATCH * CAP * 8 + fixed > ws_size && CAP > 512) CAP >>= 1;

  uint2* cand = (uint2*)d_ws;
  int* cnt   = (int*)((char*)d_ws + (size_t)NBATCH * CAP * 8);
  int* flagp = cnt + NBATCH;
  u16* Ahi   = (u16*)(flagp + NBATCH);
  u16* Alo   = Ahi + (size_t)NBATCH * DIM;

  {
    int total4 = NQ * DIM / 4 + nbatch * DIM / 4;
    prep_kernel<<<(total4 + 255) / 256, 256, 0, stream>>>(
        features, qfeat, Bhi, Blo, Ahi, Alo, cnt, out);
  }

  gemm_mfma<<<(NBATCH / GM) * (NQ / GM), 256, 0, stream>>>(
      Ahi, Alo, Bhi, Blo, cand, cnt, CAP);

  select_kernel<<<nbatch, 256, 0, stream>>>(cand, cnt, flagp, labels, qlab,
                                            out, inv_n, CAP);

  fallback_kernel<<<nbatch, 256, 0, stream>>>(features, labels, qfeat, qlab,
                                              flagp, out, inv_n);

  copy_kernel<<<(int)(((long long)NQ * DIM + NQ + 255) / 256), 256, 0, stream>>>(
      features, labels, qfeat, qlab, qptr, out);
}

// Round 4
// 268.623 us; speedup vs baseline: 1.7439x; 1.7439x over previous
//
#include <hip/hip_runtime.h>
#include <math.h>

// Problem constants
#define NQ     65536
#define DIM    256
#define NBATCH 512
#define KNN    200
#define NCLS   1000
#define TSEL   0.14f     // candidate threshold (top-200 boundary ~0.17)

#define GM  128
#define GK  32
#define NTN (NQ / GM)    // 512 bn tiles

typedef unsigned short u16;
typedef unsigned long long u64;
typedef __attribute__((ext_vector_type(8))) short short8;
typedef __attribute__((ext_vector_type(4))) float f32x4;

// out layout: [0] accuracy | [1..1+NQ*DIM) features | [..+NQ) labels | [last] ptr

__device__ __forceinline__ u16 f2bf(float x) {
  unsigned u = __float_as_uint(x);
  return (u16)((u + 0x7FFFu + ((u >> 16) & 1u)) >> 16);
}
__device__ __forceinline__ float bf2f(u16 h) {
  return __uint_as_float(((unsigned)h) << 16);
}
__device__ __forceinline__ void load_lds16(const void* g, void* l) {
  __builtin_amdgcn_global_load_lds(
      (const __attribute__((address_space(1))) unsigned int*)g,
      (__attribute__((address_space(3))) unsigned int*)l, 16, 0, 0);
}

// ---------------------------------------------------------------------------
// 0. prep: split A/B into bf16 hi/lo; zero flag[] and accuracy
// ---------------------------------------------------------------------------
__global__ __launch_bounds__(256) void prep_kernel(
    const float* __restrict__ feat, const float* __restrict__ qf,
    u16* __restrict__ Bhi, u16* __restrict__ Blo,
    u16* __restrict__ Ahi, u16* __restrict__ Alo,
    int* __restrict__ flag, float* __restrict__ out)
{
  int idx = blockIdx.x * 256 + threadIdx.x;
  const int NB4 = NQ * DIM / 4;
  const int NA4 = NBATCH * DIM / 4;
  if (idx < NB4) {
    float4 v = ((const float4*)qf)[idx];
    ushort4 h, l;
    h.x = f2bf(v.x); l.x = f2bf(v.x - bf2f(h.x));
    h.y = f2bf(v.y); l.y = f2bf(v.y - bf2f(h.y));
    h.z = f2bf(v.z); l.z = f2bf(v.z - bf2f(h.z));
    h.w = f2bf(v.w); l.w = f2bf(v.w - bf2f(h.w));
    ((ushort4*)Bhi)[idx] = h;
    ((ushort4*)Blo)[idx] = l;
  } else if (idx < NB4 + NA4) {
    int j = idx - NB4;
    float4 v = ((const float4*)feat)[j];
    ushort4 h, l;
    h.x = f2bf(v.x); l.x = f2bf(v.x - bf2f(h.x));
    h.y = f2bf(v.y); l.y = f2bf(v.y - bf2f(h.y));
    h.z = f2bf(v.z); l.z = f2bf(v.z - bf2f(h.z));
    h.w = f2bf(v.w); l.w = f2bf(v.w - bf2f(h.w));
    ((ushort4*)Ahi)[j] = h;
    ((ushort4*)Alo)[j] = l;
  }
  if (idx < NBATCH) flag[idx] = 0;
  if (idx == 0) out[0] = 0.0f;
}

// ---------------------------------------------------------------------------
// 1. split-bf16 MFMA GEMM; epilogue counts survivors via LDS atomics and
//    stores them into the block's EXCLUSIVE slot range cand[row][bn][0..SLOT).
//    No global atomics. XCD swizzle: same-bn blocks spaced 8 ids apart.
// ---------------------------------------------------------------------------
__global__ __launch_bounds__(256) void gemm_mfma(
    const u16* __restrict__ Ahi, const u16* __restrict__ Alo,
    const u16* __restrict__ Bhi, const u16* __restrict__ Blo,
    uint2* __restrict__ cand, int* __restrict__ cnt2,
    int* __restrict__ flag, int SLOT)
{
  __shared__ u16 sA[2][GM][GK];
  __shared__ u16 sB[2][GM][GK];
  __shared__ int lcnt[GM];

  const int tid  = threadIdx.x;
  const int wave = tid >> 6, lane = tid & 63;
  // d = ((bn>>3)*4 + bm)*8 + (bn&7): bm strides of 8 dispatch ids share an XCD
  const int d  = blockIdx.x;
  const int bm = (d >> 3) & 3;
  const int bn = (d & 7) | ((d >> 5) << 3);

  const u16* srcBase;
  u16* ldsBase;
  if (wave == 0)      { srcBase = Ahi + (size_t)bm * GM * DIM; ldsBase = &sA[0][0][0]; }
  else if (wave == 1) { srcBase = Alo + (size_t)bm * GM * DIM; ldsBase = &sA[1][0][0]; }
  else if (wave == 2) { srcBase = Bhi + (size_t)bn * GM * DIM; ldsBase = &sB[0][0][0]; }
  else                { srcBase = Blo + (size_t)bn * GM * DIM; ldsBase = &sB[1][0][0]; }
  const u16* src = srcBase + (lane >> 2) * DIM + (lane & 3) * 8;

  const int wm = (wave & 1) * 64, wn = (wave >> 1) * 64;
  const int fr = lane & 15;
  const int fq = lane >> 4;

  f32x4 acc[4][4] = {};

  for (int kk = 0; kk < DIM; kk += GK) {
    const u16* s = src + kk;
#pragma unroll
    for (int g = 0; g < 8; ++g)
      load_lds16(s + g * 16 * DIM, ldsBase + g * 512);
    __syncthreads();

    short8 ah[4], al[4], bh[4], bl[4];
#pragma unroll
    for (int i = 0; i < 4; ++i) {
      ah[i] = *(const short8*)&sA[0][wm + i * 16 + fr][fq * 8];
      al[i] = *(const short8*)&sA[1][wm + i * 16 + fr][fq * 8];
      bh[i] = *(const short8*)&sB[0][wn + i * 16 + fr][fq * 8];
      bl[i] = *(const short8*)&sB[1][wn + i * 16 + fr][fq * 8];
    }
#pragma unroll
    for (int i = 0; i < 4; ++i)
#pragma unroll
      for (int j = 0; j < 4; ++j) {
        acc[i][j] = __builtin_amdgcn_mfma_f32_16x16x32_bf16(ah[i], bh[j], acc[i][j], 0, 0, 0);
        acc[i][j] = __builtin_amdgcn_mfma_f32_16x16x32_bf16(ah[i], bl[j], acc[i][j], 0, 0, 0);
        acc[i][j] = __builtin_amdgcn_mfma_f32_16x16x32_bf16(al[i], bh[j], acc[i][j], 0, 0, 0);
        acc[i][j] = __builtin_amdgcn_mfma_f32_16x16x32_bf16(al[i], bl[j], acc[i][j], 0, 0, 0);
      }
    __syncthreads();
  }

  // epilogue: D row = fq*4+r (m side), col = fr (n side) [verified R2]
  for (int i = tid; i < GM; i += 256) lcnt[i] = 0;
  __syncthreads();

  const int lrow0 = wm + fq * 4;        // local row base
  const int ccol  = bn * GM + wn + fr;  // global col base
#pragma unroll
  for (int i = 0; i < 4; ++i)
#pragma unroll
    for (int j = 0; j < 4; ++j)
#pragma unroll
      for (int r = 0; r < 4; ++r) {
        float v = acc[i][j][r];
        if (v > TSEL) {
          int lr  = lrow0 + i * 16 + r;
          int col = ccol + j * 16;
          int p = atomicAdd(&lcnt[lr], 1);     // LDS atomic — cheap
          if (p < SLOT)
            cand[((size_t)(bm * GM + lr) * NTN + bn) * SLOT + p] =
                make_uint2(__float_as_uint(v), (unsigned)col);
          else
            flag[bm * GM + lr] = 1;            // rare overflow -> fallback row
        }
      }
  __syncthreads();
  if (tid < GM) {
    int c = lcnt[tid];
    cnt2[(size_t)(bm * GM + tid) * NTN + bn] = c < SLOT ? c : SLOT;
  }
}

// ---------------------------------------------------------------------------
// 2. select: gather ~820 candidates from the slotted lists, exact top-200.
// ---------------------------------------------------------------------------
#define NBSEL 2048
#define CCAP  2048

__global__ __launch_bounds__(256) void select_kernel(
    const uint2* __restrict__ cand, const int* __restrict__ cnt2,
    int* __restrict__ flag, const int* __restrict__ labels,
    const int* __restrict__ qlab, float* __restrict__ out,
    float inv_n, int SLOT)
{
  __shared__ int   hist[NBSEL];
  __shared__ int   seg[256];
  __shared__ float candV[CCAP];
  __shared__ int   candI[CCAP];
  __shared__ float votes[NCLS];
  __shared__ int   s_b, s_cnt, s_sel;
  __shared__ u64   s_best;

  const int tid = threadIdx.x;
  const int row = blockIdx.x;
  if (flag[row]) return;                       // overflow -> fallback handles

  const int*  rowcnt  = cnt2 + (size_t)row * NTN;
  const uint2* rowcand = cand + (size_t)row * NTN * SLOT;

  for (int i = tid; i < NBSEL; i += 256) hist[i] = 0;
  if (tid == 0) { s_b = 0; s_cnt = 0; s_sel = 0; s_best = 0ull; }
  __syncthreads();

  // gather: 2 tiles per thread, one LDS atomic per non-empty tile
  for (int t = tid; t < NTN; t += 256) {
    int c = rowcnt[t];
    if (c > 0) {
      int p = atomicAdd(&s_cnt, c);
      for (int k = 0; k < c; ++k) {
        if (p + k < CCAP) {
          uint2 e = rowcand[(size_t)t * SLOT + k];
          candV[p + k] = __uint_as_float(e.x);
          candI[p + k] = (int)e.y;
        }
      }
    }
  }
  __syncthreads();
  const int n = s_cnt;
  if (n < KNN || n > CCAP) { if (tid == 0) flag[row] = 1; return; }

  // histogram over (TSEL, ~1]
  const float SSCALE = (float)NBSEL / (1.001f - TSEL);
  for (int i = tid; i < n; i += 256) {
    int b = (int)((candV[i] - TSEL) * SSCALE);
    b = b < 0 ? 0 : (b > NBSEL - 1 ? NBSEL - 1 : b);
    atomicAdd(&hist[b], 1);
  }
  __syncthreads();

  { int s = 0;
#pragma unroll
    for (int i = 0; i < 8; ++i) s += hist[tid * 8 + i];
    seg[tid] = s; }
  __syncthreads();
  for (int off = 1; off < 256; off <<= 1) {
    int t = (tid + off < 256) ? seg[tid + off] : 0;
    __syncthreads();
    seg[tid] += t;
    __syncthreads();
  }
  { int run = (tid < 255) ? seg[tid + 1] : 0;
    for (int i = tid * 8 + 7; i >= tid * 8; --i) {
      run += hist[i];
      if (run >= KNN) { atomicMax(&s_b, i); break; }
    } }
  __syncthreads();
  const int bstar = s_b;

  // collect survivors (>= bstar) as u64 keys into front of a shared array
  __shared__ u64 ck[1024];
  for (int i = tid; i < n; i += 256) {
    float v = candV[i];
    int b = (int)((v - TSEL) * SSCALE);
    b = b < 0 ? 0 : (b > NBSEL - 1 ? NBSEL - 1 : b);
    if (b >= bstar) {
      int p = atomicAdd(&s_sel, 1);
      if (p < 1024)
        ck[p] = ((u64)__float_as_uint(v) << 32) |
                (u64)(0xFFFFFFFFu - (unsigned)candI[i]);
    }
  }
  __syncthreads();
  int m = s_sel;
  if (m > 1024) { if (tid == 0) flag[row] = 1; return; }

  int P = 256; while (P < m) P <<= 1;
  for (int i = tid; i < P; i += 256) if (i >= m) ck[i] = 0ull;
  __syncthreads();
  for (int k = 2; k <= P; k <<= 1) {
    for (int j = k >> 1; j > 0; j >>= 1) {
      for (int i = tid; i < P; i += 256) {
        int ixj = i ^ j;
        if (ixj > i) {
          u64 a = ck[i], b = ck[ixj];
          bool up = ((i & k) == 0);            // descending
          if (up ? (a < b) : (a > b)) { ck[i] = b; ck[ixj] = a; }
        }
      }
      __syncthreads();
    }
  }

  for (int c = tid; c < NCLS; c += 256) votes[c] = 0.0f;
  __syncthreads();
  for (int i = tid; i < KNN; i += 256) {
    u64 key = ck[i];
    float v = __uint_as_float((unsigned)(key >> 32));
    int col = (int)(0xFFFFFFFFu - (unsigned)(key & 0xFFFFFFFFull));
    atomicAdd(&votes[qlab[col]], expf(v * (1.0f / 0.07f)));
  }
  __syncthreads();

  u64 key = 0ull;
  for (int c = tid; c < NCLS; c += 256) {
    u64 k2 = ((u64)__float_as_uint(votes[c]) << 32) |
             (u64)(0xFFFFFFFFu - (unsigned)c);
    if (k2 > key) key = k2;
  }
  for (int off = 32; off > 0; off >>= 1) {
    u64 o = __shfl_down(key, off, 64);
    if (o > key) key = o;
  }
  if ((tid & 63) == 0) atomicMax(&s_best, key);
  __syncthreads();
  if (tid == 0) {
    int cls = (int)(0xFFFFFFFFu - (unsigned)(s_best & 0xFFFFFFFFull));
    if (cls == labels[row]) atomicAdd(out, inv_n);
  }
}

// ---------------------------------------------------------------------------
// 2b. fallback: exact f32 recompute + selection for flagged rows (rare).
// ---------------------------------------------------------------------------
#define FCAP 2048

__global__ __launch_bounds__(256) void fallback_kernel(
    const float* __restrict__ feat, const int* __restrict__ labels,
    const float* __restrict__ qf, const int* __restrict__ qlab,
    const int* __restrict__ flag, float* __restrict__ out, float inv_n)
{
  const int row = blockIdx.x;
  if (!flag[row]) return;

  __shared__ float frow[DIM];
  __shared__ int   hist[NBSEL];
  __shared__ int   seg[256];
  __shared__ float candV[FCAP];
  __shared__ int   candI[FCAP];
  __shared__ float votes[NCLS];
  __shared__ int   s_b, s_cnt;
  __shared__ u64   s_best;

  const int tid = threadIdx.x;
  frow[tid] = feat[(size_t)row * DIM + tid];
  for (int i = tid; i < NBSEL; i += 256) hist[i] = 0;
  if (tid == 0) { s_b = 0; s_cnt = 0; s_best = 0ull; }
  __syncthreads();

  for (int q = tid; q < NQ; q += 256) {
    const float4* qr = (const float4*)(qf + (size_t)q * DIM);
    const float4* fr = (const float4*)frow;
    float s = 0.0f;
#pragma unroll
    for (int t = 0; t < DIM / 4; ++t) {
      float4 a = fr[t], b = qr[t];
      s = fmaf(a.x, b.x, s); s = fmaf(a.y, b.y, s);
      s = fmaf(a.z, b.z, s); s = fmaf(a.w, b.w, s);
    }
    int bin = (int)((s + 1.0f) * (NBSEL * 0.5f));
    bin = bin < 0 ? 0 : (bin > NBSEL - 1 ? NBSEL - 1 : bin);
    atomicAdd(&hist[bin], 1);
  }
  __syncthreads();

  { int s = 0;
#pragma unroll
    for (int i = 0; i < 8; ++i) s += hist[tid * 8 + i];
    seg[tid] = s; }
  __syncthreads();
  for (int off = 1; off < 256; off <<= 1) {
    int t = (tid + off < 256) ? seg[tid + off] : 0;
    __syncthreads();
    seg[tid] += t;
    __syncthreads();
  }
  { int run = (tid < 255) ? seg[tid + 1] : 0;
    for (int i = tid * 8 + 7; i >= tid * 8; --i) {
      run += hist[i];
      if (run >= KNN) { atomicMax(&s_b, i); break; }
    } }
  __syncthreads();
  const int bstar = s_b;

  for (int q = tid; q < NQ; q += 256) {
    const float4* qr = (const float4*)(qf + (size_t)q * DIM);
    const float4* fr = (const float4*)frow;
    float s = 0.0f;
#pragma unroll
    for (int t = 0; t < DIM / 4; ++t) {
      float4 a = fr[t], b = qr[t];
      s = fmaf(a.x, b.x, s); s = fmaf(a.y, b.y, s);
      s = fmaf(a.z, b.z, s); s = fmaf(a.w, b.w, s);
    }
    int bin = (int)((s + 1.0f) * (NBSEL * 0.5f));
    bin = bin < 0 ? 0 : (bin > NBSEL - 1 ? NBSEL - 1 : bin);
    if (bin >= bstar) {
      int p = atomicAdd(&s_cnt, 1);
      if (p < FCAP) { candV[p] = s; candI[p] = q; }
    }
  }
  __syncthreads();
  int m = s_cnt < FCAP ? s_cnt : FCAP;

  int P = 256; while (P < m) P <<= 1;
  for (int i = tid; i < P; i += 256)
    if (i >= m) { candV[i] = -INFINITY; candI[i] = 0x7fffffff; }
  __syncthreads();
  for (int k = 2; k <= P; k <<= 1) {
    for (int j = k >> 1; j > 0; j >>= 1) {
      for (int i = tid; i < P; i += 256) {
        int ixj = i ^ j;
        if (ixj > i) {
          float va = candV[i], vb = candV[ixj];
          int ia = candI[i], ib = candI[ixj];
          bool aFirst = (va > vb) || (va == vb && ia < ib);
          bool up = ((i & k) == 0);
          if (up ? !aFirst : aFirst) {
            candV[i] = vb; candV[ixj] = va;
            candI[i] = ib; candI[ixj] = ia;
          }
        }
      }
      __syncthreads();
    }
  }

  for (int c = tid; c < NCLS; c += 256) votes[c] = 0.0f;
  __syncthreads();
  for (int i = tid; i < KNN; i += 256)
    atomicAdd(&votes[qlab[candI[i]]], expf(candV[i] * (1.0f / 0.07f)));
  __syncthreads();

  u64 key = 0ull;
  for (int c = tid; c < NCLS; c += 256) {
    u64 k2 = ((u64)__float_as_uint(votes[c]) << 32) |
             (u64)(0xFFFFFFFFu - (unsigned)c);
    if (k2 > key) key = k2;
  }
  for (int off = 32; off > 0; off >>= 1) {
    u64 o = __shfl_down(key, off, 64);
    if (o > key) key = o;
  }
  if ((tid & 63) == 0) atomicMax(&s_best, key);
  __syncthreads();
  if (tid == 0) {
    int cls = (int)(0xFFFFFFFFu - (unsigned)(s_best & 0xFFFFFFFFull));
    if (cls == labels[row]) atomicAdd(out, inv_n);
  }
}

// ---------------------------------------------------------------------------
// 3. final copy / queue update (LAST: overwrites B staging in out region)
// ---------------------------------------------------------------------------
__global__ __launch_bounds__(256) void copy_kernel(
    const float* __restrict__ feat, const int* __restrict__ labels,
    const float* __restrict__ qf, const int* __restrict__ ql,
    const int* __restrict__ qptr, float* __restrict__ out)
{
  const long long NFEAT = (long long)NQ * DIM;
  long long idx = (long long)blockIdx.x * blockDim.x + threadIdx.x;
  int ptr = qptr[0];

  if (idx < NFEAT) {
    long long row = idx >> 8;
    int col = (int)(idx & (DIM - 1));
    int d = ((int)row - ptr) & (NQ - 1);
    float v = (d < NBATCH) ? feat[(long long)d * DIM + col] : qf[idx];
    out[1 + idx] = v;
  } else if (idx < NFEAT + NQ) {
    int i = (int)(idx - NFEAT);
    int d = (i - ptr) & (NQ - 1);
    int v = (d < NBATCH) ? labels[d] : ql[i];
    out[1 + NFEAT + i] = (float)v;
  }
  if (idx == 0)
    out[1 + NFEAT + NQ] = (float)((ptr + NBATCH) & (NQ - 1));
}

// ---------------------------------------------------------------------------
extern "C" void kernel_launch(void* const* d_in, const int* in_sizes, int n_in,
                              void* d_out, int out_size, void* d_ws, size_t ws_size,
                              hipStream_t stream)
{
  const float* features = (const float*)d_in[0];
  const int*   labels   = (const int*)d_in[1];
  const float* qfeat    = (const float*)d_in[2];
  const int*   qlab     = (const int*)d_in[3];
  const int*   qptr     = (const int*)d_in[4];
  float* out = (float*)d_out;

  int nbatch = in_sizes[0] / DIM;             // 512
  float inv_n = 1.0f / (float)nbatch;

  // B hi/lo staged in out's feature region (overwritten by copy_kernel last)
  u16* Bhi = (u16*)(out + 4);
  u16* Blo = Bhi + (size_t)NQ * DIM;

  // ws: [cand NBATCH*NTN*SLOT uint2][cnt2 NBATCH*NTN int][flag][Ahi][Alo]
  size_t fixed = (size_t)NBATCH * NTN * 4 + NBATCH * 4 + (size_t)NBATCH * DIM * 2 * 2;
  int SLOT = 16;
  while ((size_t)NBATCH * NTN * SLOT * 8 + fixed > ws_size && SLOT > 2) SLOT >>= 1;

  uint2* cand = (uint2*)d_ws;
  int* cnt2  = (int*)((char*)d_ws + (size_t)NBATCH * NTN * SLOT * 8);
  int* flagp = cnt2 + (size_t)NBATCH * NTN;
  u16* Ahi   = (u16*)(flagp + NBATCH);
  u16* Alo   = Ahi + (size_t)NBATCH * DIM;

  {
    int total4 = NQ * DIM / 4 + nbatch * DIM / 4;
    prep_kernel<<<(total4 + 255) / 256, 256, 0, stream>>>(
        features, qfeat, Bhi, Blo, Ahi, Alo, flagp, out);
  }

  gemm_mfma<<<(NBATCH / GM) * (NQ / GM), 256, 0, stream>>>(
      Ahi, Alo, Bhi, Blo, cand, cnt2, flagp, SLOT);

  select_kernel<<<nbatch, 256, 0, stream>>>(cand, cnt2, flagp, labels, qlab,
                                            out, inv_n, SLOT);

  fallback_kernel<<<nbatch, 256, 0, stream>>>(features, labels, qfeat, qlab,
                                              flagp, out, inv_n);

  copy_kernel<<<(int)(((long long)NQ * DIM + NQ + 255) / 256), 256, 0, stream>>>(
      features, labels, qfeat, qlab, qptr, out);
}

// Round 5
// 262.948 us; speedup vs baseline: 1.7815x; 1.0216x over previous
//
#include <hip/hip_runtime.h>
#include <math.h>

// Problem constants
#define NQ     65536
#define DIM    256
#define NBATCH 512
#define KNN    200
#define NCLS   1000
#define TSEL   0.14f     // candidate threshold (top-200 boundary ~0.17)

#define GM  128
#define GK  32
#define NTN (NQ / GM)    // 512 bn tiles

typedef unsigned short u16;
typedef unsigned long long u64;
typedef __attribute__((ext_vector_type(8))) short short8;
typedef __attribute__((ext_vector_type(4))) float f32x4;

// out layout: [0] accuracy | [1..1+NQ*DIM) features | [..+NQ) labels | [last] ptr

__device__ __forceinline__ u16 f2bf(float x) {
  unsigned u = __float_as_uint(x);
  return (u16)((u + 0x7FFFu + ((u >> 16) & 1u)) >> 16);
}
__device__ __forceinline__ float bf2f(u16 h) {
  return __uint_as_float(((unsigned)h) << 16);
}
__device__ __forceinline__ void load_lds16(const void* g, void* l) {
  __builtin_amdgcn_global_load_lds(
      (const __attribute__((address_space(1))) unsigned int*)g,
      (__attribute__((address_space(3))) unsigned int*)l, 16, 0, 0);
}
// out+1 is only 4B-aligned: store float4 as 4 dwords
__device__ __forceinline__ void store_f4u(float* p, float4 v) {
  p[0] = v.x; p[1] = v.y; p[2] = v.z; p[3] = v.w;
}

// ---------------------------------------------------------------------------
// 0. fused prep + queue-update copy. Reads qf ONCE; writes out features
//    (with the 512 replaced rows), out labels, ptr, B hi/lo splits (ws),
//    A hi/lo splits (ws), zeroes flag[] and accuracy.
// ---------------------------------------------------------------------------
__global__ __launch_bounds__(256) void prep_copy_kernel(
    const float* __restrict__ feat, const int* __restrict__ labels,
    const float* __restrict__ qf, const int* __restrict__ ql,
    const int* __restrict__ qptr,
    u16* __restrict__ Bhi, u16* __restrict__ Blo,
    u16* __restrict__ Ahi, u16* __restrict__ Alo,
    int* __restrict__ flag, float* __restrict__ out)
{
  const int idx = blockIdx.x * 256 + threadIdx.x;   // float4 index, < NQ*DIM/4
  const int ptr = qptr[0];
  const long long NFEAT = (long long)NQ * DIM;

  // --- queue features: out = old queue except rows (ptr..ptr+511)%NQ ---
  {
    float4 qv = ((const float4*)qf)[idx];
    int row = idx >> 6;                 // / (DIM/4)
    int c4  = idx & 63;
    int d = (row - ptr) & (NQ - 1);
    float4 ov = qv;
    if (d < NBATCH) ov = ((const float4*)feat)[d * 64 + c4];
    store_f4u(out + 1 + 4 * (long long)idx, ov);

    // --- B split (ALWAYS old queue values) ---
    ushort4 h, l;
    h.x = f2bf(qv.x); l.x = f2bf(qv.x - bf2f(h.x));
    h.y = f2bf(qv.y); l.y = f2bf(qv.y - bf2f(h.y));
    h.z = f2bf(qv.z); l.z = f2bf(qv.z - bf2f(h.z));
    h.w = f2bf(qv.w); l.w = f2bf(qv.w - bf2f(h.w));
    ((ushort4*)Bhi)[idx] = h;
    ((ushort4*)Blo)[idx] = l;
  }

  // --- A split (features) ---
  if (idx < NBATCH * DIM / 4) {
    float4 v = ((const float4*)feat)[idx];
    ushort4 h, l;
    h.x = f2bf(v.x); l.x = f2bf(v.x - bf2f(h.x));
    h.y = f2bf(v.y); l.y = f2bf(v.y - bf2f(h.y));
    h.z = f2bf(v.z); l.z = f2bf(v.z - bf2f(h.z));
    h.w = f2bf(v.w); l.w = f2bf(v.w - bf2f(h.w));
    ((ushort4*)Ahi)[idx] = h;
    ((ushort4*)Alo)[idx] = l;
  }

  // --- labels ---
  if (idx < NQ) {
    int d = (idx - ptr) & (NQ - 1);
    int v = (d < NBATCH) ? labels[d] : ql[idx];
    out[1 + NFEAT + idx] = (float)v;
  }

  if (idx < NBATCH) flag[idx] = 0;
  if (idx == 0) {
    out[0] = 0.0f;
    out[1 + NFEAT + NQ] = (float)((ptr + NBATCH) & (NQ - 1));
  }
}

// ---------------------------------------------------------------------------
// 1. split-bf16 MFMA GEMM; epilogue: LDS-counted slotted candidate append.
//    XCD swizzle: same-bn blocks spaced 8 dispatch ids apart.
// ---------------------------------------------------------------------------
__global__ __launch_bounds__(256) void gemm_mfma(
    const u16* __restrict__ Ahi, const u16* __restrict__ Alo,
    const u16* __restrict__ Bhi, const u16* __restrict__ Blo,
    uint2* __restrict__ cand, int* __restrict__ cnt2,
    int* __restrict__ flag, int SLOT)
{
  __shared__ u16 sA[2][GM][GK];
  __shared__ u16 sB[2][GM][GK];
  __shared__ int lcnt[GM];

  const int tid  = threadIdx.x;
  const int wave = tid >> 6, lane = tid & 63;
  const int d  = blockIdx.x;
  const int bm = (d >> 3) & 3;
  const int bn = (d & 7) | ((d >> 5) << 3);

  for (int i = tid; i < GM; i += 256) lcnt[i] = 0;   // visible after 1st barrier

  const u16* srcBase;
  u16* ldsBase;
  if (wave == 0)      { srcBase = Ahi + (size_t)bm * GM * DIM; ldsBase = &sA[0][0][0]; }
  else if (wave == 1) { srcBase = Alo + (size_t)bm * GM * DIM; ldsBase = &sA[1][0][0]; }
  else if (wave == 2) { srcBase = Bhi + (size_t)bn * GM * DIM; ldsBase = &sB[0][0][0]; }
  else                { srcBase = Blo + (size_t)bn * GM * DIM; ldsBase = &sB[1][0][0]; }
  const u16* src = srcBase + (lane >> 2) * DIM + (lane & 3) * 8;

  const int wm = (wave & 1) * 64, wn = (wave >> 1) * 64;
  const int fr = lane & 15;
  const int fq = lane >> 4;

  f32x4 acc[4][4] = {};

  for (int kk = 0; kk < DIM; kk += GK) {
    const u16* s = src + kk;
#pragma unroll
    for (int g = 0; g < 8; ++g)
      load_lds16(s + g * 16 * DIM, ldsBase + g * 512);
    __syncthreads();

    short8 ah[4], al[4], bh[4], bl[4];
#pragma unroll
    for (int i = 0; i < 4; ++i) {
      ah[i] = *(const short8*)&sA[0][wm + i * 16 + fr][fq * 8];
      al[i] = *(const short8*)&sA[1][wm + i * 16 + fr][fq * 8];
      bh[i] = *(const short8*)&sB[0][wn + i * 16 + fr][fq * 8];
      bl[i] = *(const short8*)&sB[1][wn + i * 16 + fr][fq * 8];
    }
#pragma unroll
    for (int i = 0; i < 4; ++i)
#pragma unroll
      for (int j = 0; j < 4; ++j) {
        acc[i][j] = __builtin_amdgcn_mfma_f32_16x16x32_bf16(ah[i], bh[j], acc[i][j], 0, 0, 0);
        acc[i][j] = __builtin_amdgcn_mfma_f32_16x16x32_bf16(ah[i], bl[j], acc[i][j], 0, 0, 0);
        acc[i][j] = __builtin_amdgcn_mfma_f32_16x16x32_bf16(al[i], bh[j], acc[i][j], 0, 0, 0);
        acc[i][j] = __builtin_amdgcn_mfma_f32_16x16x32_bf16(al[i], bl[j], acc[i][j], 0, 0, 0);
      }
    __syncthreads();
  }

  // epilogue: D row = fq*4+r (m side), col = fr (n side) [verified R2]
  const int lrow0 = wm + fq * 4;
  const int ccol  = bn * GM + wn + fr;
#pragma unroll
  for (int i = 0; i < 4; ++i)
#pragma unroll
    for (int j = 0; j < 4; ++j)
#pragma unroll
      for (int r = 0; r < 4; ++r) {
        float v = acc[i][j][r];
        if (v > TSEL) {
          int lr  = lrow0 + i * 16 + r;
          int col = ccol + j * 16;
          int p = atomicAdd(&lcnt[lr], 1);
          if (p < SLOT)
            cand[((size_t)(bm * GM + lr) * NTN + bn) * SLOT + p] =
                make_uint2(__float_as_uint(v), (unsigned)col);
          else
            flag[bm * GM + lr] = 1;
        }
      }
  __syncthreads();
  if (tid < GM) {
    int c = lcnt[tid];
    cnt2[(size_t)(bm * GM + tid) * NTN + bn] = c < SLOT ? c : SLOT;
  }
}

// ---------------------------------------------------------------------------
// 2. select (with inline exact-recompute fallback): one block per row.
// ---------------------------------------------------------------------------
#define NBSEL 2048
#define CCAP  2048

__global__ __launch_bounds__(256) void select_kernel(
    const uint2* __restrict__ cand, const int* __restrict__ cnt2,
    const int* __restrict__ flag, const int* __restrict__ labels,
    const int* __restrict__ qlab, const float* __restrict__ qf,
    const float* __restrict__ feat, float* __restrict__ out,
    float inv_n, int SLOT)
{
  __shared__ int   hist[NBSEL];
  __shared__ int   seg[256];
  __shared__ float candV[CCAP];
  __shared__ int   candI[CCAP];
  __shared__ float votes[NCLS];
  __shared__ u64   ck[1024];
  __shared__ float frow[DIM];
  __shared__ int   s_b, s_cnt, s_sel;
  __shared__ u64   s_best;

  const int tid = threadIdx.x;
  const int row = blockIdx.x;

  bool fb = (flag[row] != 0);           // block-uniform

  for (int i = tid; i < NBSEL; i += 256) hist[i] = 0;
  if (tid == 0) { s_b = 0; s_cnt = 0; s_sel = 0; s_best = 0ull; }
  __syncthreads();

  if (!fb) {
    // ---- gather candidates from slotted lists ----
    const int*   rowcnt  = cnt2 + (size_t)row * NTN;
    const uint2* rowcand = cand + (size_t)row * NTN * SLOT;
    for (int t = tid; t < NTN; t += 256) {
      int c = rowcnt[t];
      if (c > 0) {
        int p = atomicAdd(&s_cnt, c);
        for (int k = 0; k < c; ++k) {
          if (p + k < CCAP) {
            uint2 e = rowcand[(size_t)t * SLOT + k];
            candV[p + k] = __uint_as_float(e.x);
            candI[p + k] = (int)e.y;
          }
        }
      }
    }
    __syncthreads();
    const int n = s_cnt;
    if (n < KNN || n > CCAP) fb = true;
    else {
      // ---- histogram over (TSEL, ~1] ----
      const float SSCALE = (float)NBSEL / (1.001f - TSEL);
      for (int i = tid; i < n; i += 256) {
        int b = (int)((candV[i] - TSEL) * SSCALE);
        b = b < 0 ? 0 : (b > NBSEL - 1 ? NBSEL - 1 : b);
        atomicAdd(&hist[b], 1);
      }
      __syncthreads();
      { int s = 0;
#pragma unroll
        for (int i = 0; i < 8; ++i) s += hist[tid * 8 + i];
        seg[tid] = s; }
      __syncthreads();
      for (int off = 1; off < 256; off <<= 1) {
        int t = (tid + off < 256) ? seg[tid + off] : 0;
        __syncthreads();
        seg[tid] += t;
        __syncthreads();
      }
      { int run = (tid < 255) ? seg[tid + 1] : 0;
        for (int i = tid * 8 + 7; i >= tid * 8; --i) {
          run += hist[i];
          if (run >= KNN) { atomicMax(&s_b, i); break; }
        } }
      __syncthreads();
      const int bstar = s_b;

      for (int i = tid; i < n; i += 256) {
        float v = candV[i];
        int b = (int)((v - TSEL) * SSCALE);
        b = b < 0 ? 0 : (b > NBSEL - 1 ? NBSEL - 1 : b);
        if (b >= bstar) {
          int p = atomicAdd(&s_sel, 1);
          if (p < 1024)
            ck[p] = ((u64)__float_as_uint(v) << 32) |
                    (u64)(0xFFFFFFFFu - (unsigned)candI[i]);
        }
      }
      __syncthreads();
      int m = s_sel;
      if (m > 1024) fb = true;
      else {
        int P = 256; while (P < m) P <<= 1;
        for (int i = tid; i < P; i += 256) if (i >= m) ck[i] = 0ull;
        __syncthreads();
        for (int k = 2; k <= P; k <<= 1) {
          for (int j = k >> 1; j > 0; j >>= 1) {
            for (int i = tid; i < P; i += 256) {
              int ixj = i ^ j;
              if (ixj > i) {
                u64 a = ck[i], b = ck[ixj];
                bool up = ((i & k) == 0);       // descending
                if (up ? (a < b) : (a > b)) { ck[i] = b; ck[ixj] = a; }
              }
            }
            __syncthreads();
          }
        }
        // vote from ck
        for (int c = tid; c < NCLS; c += 256) votes[c] = 0.0f;
        __syncthreads();
        for (int i = tid; i < KNN; i += 256) {
          u64 key = ck[i];
          float v = __uint_as_float((unsigned)(key >> 32));
          int col = (int)(0xFFFFFFFFu - (unsigned)(key & 0xFFFFFFFFull));
          atomicAdd(&votes[qlab[col]], expf(v * (1.0f / 0.07f)));
        }
        __syncthreads();
      }
    }
  }

  if (fb) {
    // ---- exact f32 recompute + selection (rare / data-independent guard) ----
    if (tid < DIM) frow[tid] = feat[(size_t)row * DIM + tid];
    for (int i = tid; i < NBSEL; i += 256) hist[i] = 0;
    if (tid == 0) { s_b = 0; s_cnt = 0; }
    __syncthreads();

    for (int q = tid; q < NQ; q += 256) {
      const float4* qr = (const float4*)(qf + (size_t)q * DIM);
      const float4* fr = (const float4*)frow;
      float s = 0.0f;
#pragma unroll
      for (int t = 0; t < DIM / 4; ++t) {
        float4 a = fr[t], b = qr[t];
        s = fmaf(a.x, b.x, s); s = fmaf(a.y, b.y, s);
        s = fmaf(a.z, b.z, s); s = fmaf(a.w, b.w, s);
      }
      int bin = (int)((s + 1.0f) * (NBSEL * 0.5f));
      bin = bin < 0 ? 0 : (bin > NBSEL - 1 ? NBSEL - 1 : bin);
      atomicAdd(&hist[bin], 1);
    }
    __syncthreads();

    { int s = 0;
#pragma unroll
      for (int i = 0; i < 8; ++i) s += hist[tid * 8 + i];
      seg[tid] = s; }
    __syncthreads();
    for (int off = 1; off < 256; off <<= 1) {
      int t = (tid + off < 256) ? seg[tid + off] : 0;
      __syncthreads();
      seg[tid] += t;
      __syncthreads();
    }
    { int run = (tid < 255) ? seg[tid + 1] : 0;
      for (int i = tid * 8 + 7; i >= tid * 8; --i) {
        run += hist[i];
        if (run >= KNN) { atomicMax(&s_b, i); break; }
      } }
    __syncthreads();
    const int bstar = s_b;

    for (int q = tid; q < NQ; q += 256) {
      const float4* qr = (const float4*)(qf + (size_t)q * DIM);
      const float4* fr = (const float4*)frow;
      float s = 0.0f;
#pragma unroll
      for (int t = 0; t < DIM / 4; ++t) {
        float4 a = fr[t], b = qr[t];
        s = fmaf(a.x, b.x, s); s = fmaf(a.y, b.y, s);
        s = fmaf(a.z, b.z, s); s = fmaf(a.w, b.w, s);
      }
      int bin = (int)((s + 1.0f) * (NBSEL * 0.5f));
      bin = bin < 0 ? 0 : (bin > NBSEL - 1 ? NBSEL - 1 : bin);
      if (bin >= bstar) {
        int p = atomicAdd(&s_cnt, 1);
        if (p < CCAP) { candV[p] = s; candI[p] = q; }
      }
    }
    __syncthreads();
    int m = s_cnt < CCAP ? s_cnt : CCAP;

    int P = 256; while (P < m) P <<= 1;
    for (int i = tid; i < P; i += 256)
      if (i >= m) { candV[i] = -INFINITY; candI[i] = 0x7fffffff; }
    __syncthreads();
    for (int k = 2; k <= P; k <<= 1) {
      for (int j = k >> 1; j > 0; j >>= 1) {
        for (int i = tid; i < P; i += 256) {
          int ixj = i ^ j;
          if (ixj > i) {
            float va = candV[i], vb = candV[ixj];
            int ia = candI[i], ib = candI[ixj];
            bool aFirst = (va > vb) || (va == vb && ia < ib);
            bool up = ((i & k) == 0);
            if (up ? !aFirst : aFirst) {
              candV[i] = vb; candV[ixj] = va;
              candI[i] = ib; candI[ixj] = ia;
            }
          }
        }
        __syncthreads();
      }
    }

    for (int c = tid; c < NCLS; c += 256) votes[c] = 0.0f;
    __syncthreads();
    for (int i = tid; i < KNN; i += 256)
      atomicAdd(&votes[qlab[candI[i]]], expf(candV[i] * (1.0f / 0.07f)));
    __syncthreads();
  }

  // ---- common argmax (lowest class index on tie) + accuracy ----
  u64 key = 0ull;
  for (int c = tid; c < NCLS; c += 256) {
    u64 k2 = ((u64)__float_as_uint(votes[c]) << 32) |
             (u64)(0xFFFFFFFFu - (unsigned)c);
    if (k2 > key) key = k2;
  }
  for (int off = 32; off > 0; off >>= 1) {
    u64 o = __shfl_down(key, off, 64);
    if (o > key) key = o;
  }
  if ((tid & 63) == 0) atomicMax(&s_best, key);
  __syncthreads();
  if (tid == 0) {
    int cls = (int)(0xFFFFFFFFu - (unsigned)(s_best & 0xFFFFFFFFull));
    if (cls == labels[row]) atomicAdd(out, inv_n);
  }
}

// ---------------------------------------------------------------------------
extern "C" void kernel_launch(void* const* d_in, const int* in_sizes, int n_in,
                              void* d_out, int out_size, void* d_ws, size_t ws_size,
                              hipStream_t stream)
{
  const float* features = (const float*)d_in[0];
  const int*   labels   = (const int*)d_in[1];
  const float* qfeat    = (const float*)d_in[2];
  const int*   qlab     = (const int*)d_in[3];
  const int*   qptr     = (const int*)d_in[4];
  float* out = (float*)d_out;

  int nbatch = in_sizes[0] / DIM;             // 512
  float inv_n = 1.0f / (float)nbatch;

  // ws layout: [Bhi 32MB][Blo 32MB][cand][cnt2 1MB][flag 2KB][Ahi][Alo]
  size_t bBytes = (size_t)NQ * DIM * 2;                 // 32 MiB each
  size_t fixed  = 2 * bBytes + (size_t)NBATCH * NTN * 4 + NBATCH * 4 +
                  (size_t)NBATCH * DIM * 2 * 2;
  int SLOT = 16;
  while ((size_t)NBATCH * NTN * SLOT * 8 + fixed > ws_size && SLOT > 2) SLOT >>= 1;

  u16*   Bhi  = (u16*)d_ws;
  u16*   Blo  = Bhi + (size_t)NQ * DIM;
  uint2* cand = (uint2*)((char*)d_ws + 2 * bBytes);
  int*   cnt2 = (int*)((char*)cand + (size_t)NBATCH * NTN * SLOT * 8);
  int*   flagp = cnt2 + (size_t)NBATCH * NTN;
  u16*   Ahi  = (u16*)(flagp + NBATCH);
  u16*   Alo  = Ahi + (size_t)NBATCH * DIM;

  prep_copy_kernel<<<NQ * DIM / 4 / 256, 256, 0, stream>>>(
      features, labels, qfeat, qlab, qptr, Bhi, Blo, Ahi, Alo, flagp, out);

  gemm_mfma<<<(NBATCH / GM) * (NQ / GM), 256, 0, stream>>>(
      Ahi, Alo, Bhi, Blo, cand, cnt2, flagp, SLOT);

  select_kernel<<<nbatch, 256, 0, stream>>>(cand, cnt2, flagp, labels, qlab,
                                            qfeat, features, out, inv_n, SLOT);
}